// Round 1
// baseline (270.147 us; speedup 1.0000x reference)
//
#include <hip/hip_runtime.h>

#define NCH   10000
#define NDV   1000000
#define BATCH 8192
#define KNB   64
#define EMB   16
#define CHD   16
#define DVD   20
#define H1    64
#define H2    64
#define AH    84
#define IN1   32
#define IN2   132

// One block per vertex. 256 threads: threads [0,128) handle the "bot" branch,
// [128,256) the "normal" branch. Within a half, thread j owns feature j of the
// 132-wide neighbor feature vector (j<20: device_dense col j; j>=20: embedding
// table (j-20)/16, column (j-20)%16). Threads j<4 additionally own features
// 128+j (table 6, cols 12..15). Mask exploited: loop only first cnt neighbors.
__global__ __launch_bounds__(256) void gconv_kernel(
    const float* __restrict__ channel_dense,
    const float* __restrict__ device_dense,
    const float* __restrict__ channel_id_emb,
    const float* __restrict__ t0, const float* __restrict__ t1,
    const float* __restrict__ t2, const float* __restrict__ t3,
    const float* __restrict__ t4, const float* __restrict__ t5,
    const float* __restrict__ t6,
    const float* __restrict__ W_agg,  const float* __restrict__ b_agg,
    const float* __restrict__ W_self, const float* __restrict__ b_self,
    const float* __restrict__ W_attn, const float* __restrict__ b_attn,
    const float* __restrict__ W_attn2,
    const int* __restrict__ channel_ids,
    const int* __restrict__ device_cat,
    const int* __restrict__ vertices,
    const int* __restrict__ bot_neibrs,
    const int* __restrict__ normal_neibrs,
    const int* __restrict__ bot_counts,
    const int* __restrict__ normal_counts,
    float* __restrict__ out)
{
    const int v    = blockIdx.x;
    const int t    = threadIdx.x;
    const int half = t >> 7;       // 0 = bot, 1 = normal
    const int j    = t & 127;

    __shared__ float chv[IN1];        // channel self features
    __shared__ float fsum[2][IN2];    // per-branch feature sums
    __shared__ float hbuf[2][H2];     // per-branch aggregated h
    __shared__ float selfb[H1];       // ch_v @ W_self + b_self
    __shared__ float sred[2][2];      // per-branch per-wave score partials

    const int vert = vertices[v];

    // stage channel self features (32 floats)
    if (t < CHD) {
        chv[t] = channel_dense[vert * CHD + t];
    } else if (t < IN1) {
        chv[t] = channel_id_emb[channel_ids[vert] * EMB + (t - CHD)];
    }

    const int* neibrs = half ? normal_neibrs : bot_neibrs;
    int cnt = half ? normal_counts[v] : bot_counts[v];
    if (cnt > KNB) cnt = KNB;
    if (cnt < 1)   cnt = 1;

    // per-thread feature assignment (done once, outside the gather loop)
    const bool isDense = (j < DVD);
    const float* tbl = nullptr;
    int tsel = 0, col = 0;
    if (!isDense) {
        const int e = j - DVD;        // 0..107
        tsel = e >> 4;                // table 0..6
        col  = e & 15;
        switch (tsel) {               // switch, not array: avoid scratch (rule #20)
            case 0: tbl = t0; break;
            case 1: tbl = t1; break;
            case 2: tbl = t2; break;
            case 3: tbl = t3; break;
            case 4: tbl = t4; break;
            case 5: tbl = t5; break;
            default: tbl = t6; break;
        }
    }

    // gather + accumulate (only first cnt neighbors — mask exploited)
    float acc0 = 0.f, acc1 = 0.f;
    const int nb = v * KNB;
    #pragma unroll 4
    for (int k = 0; k < cnt; ++k) {
        const int n = neibrs[nb + k];                 // wave-uniform address
        const int* crow = device_cat + (long)n * 7;
        if (isDense) {
            acc0 += device_dense[(long)n * DVD + j];  // 20 lanes, contiguous row
        } else {
            acc0 += tbl[crow[tsel] * EMB + col];      // 16 lanes, contiguous row
        }
        if (j < 4) {                                  // features 128..131: table 6
            acc1 += t6[crow[6] * EMB + 12 + j];
        }
    }
    fsum[half][j] = acc0;
    if (j < 4) fsum[half][128 + j] = acc1;
    __syncthreads();

    // phase 2: h = mean @ W_agg + b_agg ; selfb = ch_v @ W_self + b_self
    const float invc = 1.0f / (float)cnt;
    if (j < H2) {
        float a = 0.f;
        #pragma unroll 4
        for (int f = 0; f < IN2; ++f)
            a = fmaf(fsum[half][f], W_agg[f * H2 + j], a);
        hbuf[half][j] = fmaf(a, invc, b_agg[j]);
    } else if (half == 0) {
        const int jj = j - 64;
        float a = b_self[jj];
        #pragma unroll
        for (int f = 0; f < IN1; ++f)
            a = fmaf(chv[f], W_self[f * H1 + jj], a);
        selfb[jj] = a;
    }
    __syncthreads();

    // phase 3: attention scores (b_attn2 cancels in 2-way softmax; omitted)
    float partial = 0.f;
    if (j < AH) {
        float u = b_attn[j];
        #pragma unroll 4
        for (int f = 0; f < H2; ++f)
            u = fmaf(hbuf[half][f], W_attn[f * AH + j], u);
        #pragma unroll 4
        for (int f = 0; f < IN1; ++f)
            u = fmaf(chv[f], W_attn[(H2 + f) * AH + j], u);
        partial = fmaxf(u, 0.f) * W_attn2[j];
    }
    #pragma unroll
    for (int off = 32; off > 0; off >>= 1)
        partial += __shfl_xor(partial, off, 64);
    if ((t & 63) == 0) sred[half][(t >> 6) & 1] = partial;
    __syncthreads();

    // phase 4: softmax over 2 scores, convex combo, relu(concat) output
    const float s0 = sred[0][0] + sred[0][1];
    const float s1 = sred[1][0] + sred[1][1];
    const float m  = fmaxf(s0, s1);
    const float ex0 = __expf(s0 - m), ex1 = __expf(s1 - m);
    const float rs  = 1.0f / (ex0 + ex1);
    const float a0 = ex0 * rs, a1 = ex1 * rs;
    if (t < H2) {
        const float g = a0 * hbuf[0][t] + a1 * hbuf[1][t];
        out[v * (H2 + H1) + t] = fmaxf(g, 0.f);
    } else if (t < H2 + H1) {
        out[v * (H2 + H1) + t] = fmaxf(selfb[t - H2], 0.f);
    }
}

extern "C" void kernel_launch(void* const* d_in, const int* in_sizes, int n_in,
                              void* d_out, int out_size, void* d_ws, size_t ws_size,
                              hipStream_t stream) {
    const float* channel_dense  = (const float*)d_in[0];
    const float* device_dense   = (const float*)d_in[1];
    const float* channel_id_emb = (const float*)d_in[2];
    const float* lang_emb       = (const float*)d_in[3];
    const float* plat_emb       = (const float*)d_in[4];
    const float* os_emb         = (const float*)d_in[5];
    const float* country_emb    = (const float*)d_in[6];
    const float* carrier_emb    = (const float*)d_in[7];
    const float* brand_emb      = (const float*)d_in[8];
    const float* plat_os_emb    = (const float*)d_in[9];
    const float* W_agg          = (const float*)d_in[10];
    const float* b_agg          = (const float*)d_in[11];
    const float* W_self         = (const float*)d_in[12];
    const float* b_self         = (const float*)d_in[13];
    const float* W_attn         = (const float*)d_in[14];
    const float* b_attn         = (const float*)d_in[15];
    const float* W_attn2        = (const float*)d_in[16];
    // d_in[17] = b_attn2: zero + cancels in 2-way softmax, unused
    const int* channel_ids   = (const int*)d_in[18];
    const int* device_cat    = (const int*)d_in[19];
    const int* vertices      = (const int*)d_in[20];
    const int* bot_neibrs    = (const int*)d_in[21];
    const int* normal_neibrs = (const int*)d_in[22];
    const int* bot_counts    = (const int*)d_in[23];
    const int* normal_counts = (const int*)d_in[24];
    float* out = (float*)d_out;

    gconv_kernel<<<dim3(BATCH), dim3(256), 0, stream>>>(
        channel_dense, device_dense, channel_id_emb,
        lang_emb, plat_emb, os_emb, country_emb, carrier_emb, brand_emb, plat_os_emb,
        W_agg, b_agg, W_self, b_self, W_attn, b_attn, W_attn2,
        channel_ids, device_cat, vertices, bot_neibrs, normal_neibrs,
        bot_counts, normal_counts, out);
}

// Round 2
// 158.491 us; speedup vs baseline: 1.7045x; 1.7045x over previous
//
#include <hip/hip_runtime.h>

#define NCH   10000
#define NDV   1000000
#define BATCH 8192
#define KNB   64
#define EMB   16
#define CHD   16
#define DVD   20
#define H1    64
#define H2    64
#define AH    84
#define IN1   32
#define IN2   132

// One block per vertex. 256 threads: threads [0,128) = "bot" branch, [128,256)
// = "normal". Three-phase gather to kill the dependent-load chain:
//   A1: neighbor indices -> LDS (coalesced, 1 round trip, all 64 at once)
//   A2: all 7*cnt categorical indices -> LDS (1 round trip, independent loads)
//   B : feature-parallel accumulate; every global load independent (unroll 8)
__global__ __launch_bounds__(256) void gconv_kernel(
    const float* __restrict__ channel_dense,
    const float* __restrict__ device_dense,
    const float* __restrict__ channel_id_emb,
    const float* __restrict__ t0, const float* __restrict__ t1,
    const float* __restrict__ t2, const float* __restrict__ t3,
    const float* __restrict__ t4, const float* __restrict__ t5,
    const float* __restrict__ t6,
    const float* __restrict__ W_agg,  const float* __restrict__ b_agg,
    const float* __restrict__ W_self, const float* __restrict__ b_self,
    const float* __restrict__ W_attn, const float* __restrict__ b_attn,
    const float* __restrict__ W_attn2,
    const int* __restrict__ channel_ids,
    const int* __restrict__ device_cat,
    const int* __restrict__ vertices,
    const int* __restrict__ bot_neibrs,
    const int* __restrict__ normal_neibrs,
    const int* __restrict__ bot_counts,
    const int* __restrict__ normal_counts,
    float* __restrict__ out)
{
    const int v    = blockIdx.x;
    const int t    = threadIdx.x;
    const int half = t >> 7;       // 0 = bot, 1 = normal (wave-uniform)
    const int j    = t & 127;

    __shared__ float chv[IN1];          // channel self features
    __shared__ int   nidx[2][KNB];      // neighbor indices
    __shared__ int   cats[2][KNB][7];   // categorical ids per neighbor
    __shared__ float fsum[2][IN2];      // per-branch feature sums
    __shared__ float hbuf[2][H2];       // per-branch aggregated h
    __shared__ float selfb[H1];         // ch_v @ W_self + b_self
    __shared__ float sred[2][2];        // per-branch per-wave score partials

    const int vert = vertices[v];
    const int* neibrs = half ? normal_neibrs : bot_neibrs;
    int cnt = half ? normal_counts[v] : bot_counts[v];
    if (cnt > KNB) cnt = KNB;
    if (cnt < 1)   cnt = 1;

    // ---- Phase A1: neighbor indices -> LDS (coalesced) ------------------
    if (j < KNB) {
        nidx[half][j] = (j < cnt) ? neibrs[v * KNB + j] : 0;
    } else if (half == 0) {
        // half-0 threads 64..95 stage the 32 channel-self floats in parallel
        const int c = j - KNB;
        if (c < CHD)      chv[c] = channel_dense[vert * CHD + c];
        else if (c < IN1) chv[c] = channel_id_emb[channel_ids[vert] * EMB + (c - CHD)];
    }
    __syncthreads();

    // ---- Phase A2: all categorical ids -> LDS (independent loads) -------
    {
        const int k   = j & 63;
        const int grp = j >> 6;          // 0: cat 0..3, 1: cat 4..6
        if (k < cnt) {
            const long base = (long)nidx[half][k] * 7;
            if (grp == 0) {
                cats[half][k][0] = device_cat[base + 0];
                cats[half][k][1] = device_cat[base + 1];
                cats[half][k][2] = device_cat[base + 2];
                cats[half][k][3] = device_cat[base + 3];
            } else {
                cats[half][k][4] = device_cat[base + 4];
                cats[half][k][5] = device_cat[base + 5];
                cats[half][k][6] = device_cat[base + 6];
            }
        }
    }
    __syncthreads();

    // ---- Phase B: feature-parallel gather-accumulate --------------------
    const bool isDense = (j < DVD);
    const float* tbl = nullptr;
    int tsel = 0, col = 0;
    if (!isDense) {
        const int e = j - DVD;           // 0..107
        tsel = e >> 4;                   // table 0..6
        col  = e & 15;
        switch (tsel) {                  // switch, not array: avoid scratch
            case 0: tbl = t0; break;
            case 1: tbl = t1; break;
            case 2: tbl = t2; break;
            case 3: tbl = t3; break;
            case 4: tbl = t4; break;
            case 5: tbl = t5; break;
            default: tbl = t6; break;
        }
    }

    float acc0 = 0.f, acc1 = 0.f;
    #pragma unroll 8
    for (int k = 0; k < cnt; ++k) {
        if (isDense) {
            acc0 += device_dense[(long)nidx[half][k] * DVD + j]; // 20 lanes, 80B row
        } else {
            acc0 += tbl[cats[half][k][tsel] * EMB + col];        // 16-lane 64B rows
        }
        if (j < 4) {                                             // feats 128..131
            acc1 += t6[cats[half][k][6] * EMB + 12 + j];
        }
    }
    fsum[half][j] = acc0;
    if (j < 4) fsum[half][128 + j] = acc1;
    __syncthreads();

    // ---- Phase 2: h = mean @ W_agg + b_agg ; selfb = ch_v @ W_self + b ---
    const float invc = 1.0f / (float)cnt;
    if (j < H2) {
        float a = 0.f;
        #pragma unroll 4
        for (int f = 0; f < IN2; ++f)
            a = fmaf(fsum[half][f], W_agg[f * H2 + j], a);
        hbuf[half][j] = fmaf(a, invc, b_agg[j]);
    } else if (half == 0) {
        const int jj = j - 64;
        float a = b_self[jj];
        #pragma unroll
        for (int f = 0; f < IN1; ++f)
            a = fmaf(chv[f], W_self[f * H1 + jj], a);
        selfb[jj] = a;
    }
    __syncthreads();

    // ---- Phase 3: attention scores (b_attn2 cancels in 2-way softmax) ----
    float partial = 0.f;
    if (j < AH) {
        float u = b_attn[j];
        #pragma unroll 4
        for (int f = 0; f < H2; ++f)
            u = fmaf(hbuf[half][f], W_attn[f * AH + j], u);
        #pragma unroll 4
        for (int f = 0; f < IN1; ++f)
            u = fmaf(chv[f], W_attn[(H2 + f) * AH + j], u);
        partial = fmaxf(u, 0.f) * W_attn2[j];
    }
    #pragma unroll
    for (int off = 32; off > 0; off >>= 1)
        partial += __shfl_xor(partial, off, 64);
    if ((t & 63) == 0) sred[half][(t >> 6) & 1] = partial;
    __syncthreads();

    // ---- Phase 4: 2-way softmax, convex combo, relu(concat) out ---------
    const float s0 = sred[0][0] + sred[0][1];
    const float s1 = sred[1][0] + sred[1][1];
    const float m  = fmaxf(s0, s1);
    const float ex0 = __expf(s0 - m), ex1 = __expf(s1 - m);
    const float rs  = 1.0f / (ex0 + ex1);
    const float a0 = ex0 * rs, a1 = ex1 * rs;
    if (t < H2) {
        const float g = a0 * hbuf[0][t] + a1 * hbuf[1][t];
        out[v * (H2 + H1) + t] = fmaxf(g, 0.f);
    } else if (t < H2 + H1) {
        out[v * (H2 + H1) + t] = fmaxf(selfb[t - H2], 0.f);
    }
}

extern "C" void kernel_launch(void* const* d_in, const int* in_sizes, int n_in,
                              void* d_out, int out_size, void* d_ws, size_t ws_size,
                              hipStream_t stream) {
    const float* channel_dense  = (const float*)d_in[0];
    const float* device_dense   = (const float*)d_in[1];
    const float* channel_id_emb = (const float*)d_in[2];
    const float* lang_emb       = (const float*)d_in[3];
    const float* plat_emb       = (const float*)d_in[4];
    const float* os_emb         = (const float*)d_in[5];
    const float* country_emb    = (const float*)d_in[6];
    const float* carrier_emb    = (const float*)d_in[7];
    const float* brand_emb      = (const float*)d_in[8];
    const float* plat_os_emb    = (const float*)d_in[9];
    const float* W_agg          = (const float*)d_in[10];
    const float* b_agg          = (const float*)d_in[11];
    const float* W_self         = (const float*)d_in[12];
    const float* b_self         = (const float*)d_in[13];
    const float* W_attn         = (const float*)d_in[14];
    const float* b_attn         = (const float*)d_in[15];
    const float* W_attn2        = (const float*)d_in[16];
    // d_in[17] = b_attn2: zero + cancels in 2-way softmax, unused
    const int* channel_ids   = (const int*)d_in[18];
    const int* device_cat    = (const int*)d_in[19];
    const int* vertices      = (const int*)d_in[20];
    const int* bot_neibrs    = (const int*)d_in[21];
    const int* normal_neibrs = (const int*)d_in[22];
    const int* bot_counts    = (const int*)d_in[23];
    const int* normal_counts = (const int*)d_in[24];
    float* out = (float*)d_out;

    gconv_kernel<<<dim3(BATCH), dim3(256), 0, stream>>>(
        channel_dense, device_dense, channel_id_emb,
        lang_emb, plat_emb, os_emb, country_emb, carrier_emb, brand_emb, plat_os_emb,
        W_agg, b_agg, W_self, b_self, W_attn, b_attn, W_attn2,
        channel_ids, device_cat, vertices, bot_neibrs, normal_neibrs,
        bot_counts, normal_counts, out);
}

// Round 3
// 126.907 us; speedup vs baseline: 2.1287x; 1.2489x over previous
//
#include <hip/hip_runtime.h>

#define NCH   10000
#define NDV   1000000
#define BATCH 8192
#define KNB   64
#define EMB   16
#define CHD   16
#define DVD   20
#define H1    64
#define H2    64
#define AH    84
#define IN1   32
#define IN2   132

// One block per vertex, 256 threads. Threads [0,128) = "bot", [128,256) =
// "normal". Branchless batched gather:
//   A: per-neighbor offsets (n*20, cat_c*16) -> LDS ofs[half][k][8slots]
//      (each wave loads its own neighbor indices -> no A1/A2 barrier)
//   B: feature-parallel accumulate, k tiled by 8: 8 ds_reads -> 8 independent
//      global loads -> 8 masked fmas. 132 features on exactly 128 threads:
//      lanes 124..127 own float2 column-pairs of table 6 (no divergence).
__global__ __launch_bounds__(256) void gconv_kernel(
    const float* __restrict__ channel_dense,
    const float* __restrict__ device_dense,
    const float* __restrict__ channel_id_emb,
    const float* __restrict__ t0, const float* __restrict__ t1,
    const float* __restrict__ t2, const float* __restrict__ t3,
    const float* __restrict__ t4, const float* __restrict__ t5,
    const float* __restrict__ t6,
    const float* __restrict__ W_agg,  const float* __restrict__ b_agg,
    const float* __restrict__ W_self, const float* __restrict__ b_self,
    const float* __restrict__ W_attn, const float* __restrict__ b_attn,
    const float* __restrict__ W_attn2,
    const int* __restrict__ channel_ids,
    const int* __restrict__ device_cat,
    const int* __restrict__ vertices,
    const int* __restrict__ bot_neibrs,
    const int* __restrict__ normal_neibrs,
    const int* __restrict__ bot_counts,
    const int* __restrict__ normal_counts,
    float* __restrict__ out)
{
    const int v    = blockIdx.x;
    const int t    = threadIdx.x;
    const int half = t >> 7;       // 0 = bot, 1 = normal (wave-uniform)
    const int j    = t & 127;

    __shared__ float chv[IN1];
    __shared__ int   ofs[2][KNB][8];   // [half][k][slot]: 0=n*DVD, 1+c=cat_c*EMB
    __shared__ float fsum[2][IN2];
    __shared__ float hbuf[2][H2];
    __shared__ float selfb[H1];
    __shared__ float sred[2][2];

    const int vert = vertices[v];
    const int* neibrs = half ? normal_neibrs : bot_neibrs;
    int cnt = half ? normal_counts[v] : bot_counts[v];
    if (cnt > KNB) cnt = KNB;
    if (cnt < 1)   cnt = 1;

    // ---- Phase A: offsets -> LDS (one barrier total) --------------------
    {
        const int k   = j & 63;
        const int grp = j >> 6;                     // both waves of a half
        const int n   = (k < cnt) ? neibrs[v * KNB + k] : 0;
        const long cb = (long)n * 7;
        if (grp == 0) {
            const int c0 = device_cat[cb + 0];
            const int c1 = device_cat[cb + 1];
            const int c2 = device_cat[cb + 2];
            const int c3 = device_cat[cb + 3];
            *(int4*)&ofs[half][k][0] = make_int4(n * DVD, c0 * EMB, c1 * EMB, c2 * EMB);
            ofs[half][k][4] = c3 * EMB;
        } else {
            const int c4 = device_cat[cb + 4];
            const int c5 = device_cat[cb + 5];
            const int c6 = device_cat[cb + 6];
            ofs[half][k][5] = c4 * EMB;
            *(int2*)&ofs[half][k][6] = make_int2(c5 * EMB, c6 * EMB);
        }
        if (t < IN1) {
            chv[t] = (t < CHD) ? channel_dense[vert * CHD + t]
                               : channel_id_emb[channel_ids[vert] * EMB + (t - CHD)];
        }
    }
    __syncthreads();

    // ---- per-thread feature assignment (132 feats on 128 threads) -------
    // j<20: dense col j (slot 0). 20<=j<116: tables 0..5 (slot 1+tsel).
    // 116<=j<124: t6 cols 0..7. 124<=j<128: t6 float2 col-pairs (8,9)..(14,15).
    const float* P;
    int slot, off, feat;
    bool isDouble = false;
    if (j < DVD) {
        P = device_dense; slot = 0; off = j; feat = j;
    } else if (j < 116) {
        const int e = j - DVD;
        const int tsel = e >> 4;
        off = e & 15; slot = 1 + tsel; feat = j;
        switch (tsel) {
            case 0: P = t0; break;
            case 1: P = t1; break;
            case 2: P = t2; break;
            case 3: P = t3; break;
            case 4: P = t4; break;
            default: P = t5; break;
        }
    } else if (j < 124) {
        P = t6; slot = 7; off = j - 116; feat = j;
    } else {
        P = t6; slot = 7; off = 8 + 2 * (j - 124); feat = 116 + off; isDouble = true;
    }

    // ---- Phase B: batched branchless gather-accumulate ------------------
    const int* ofsBase = &ofs[half][0][slot];       // stride 8 ints per k
    float acc0 = 0.f, acc1 = 0.f;
    for (int k0 = 0; k0 < cnt; k0 += 8) {
        int o[8];
        #pragma unroll
        for (int i = 0; i < 8; ++i)
            o[i] = ofsBase[(k0 + i) * 8];           // 8 independent ds_reads
        float va[8], vb[8];
        #pragma unroll
        for (int i = 0; i < 8; ++i) {               // 8 independent global loads
            if (isDouble) {
                const float2 u = *(const float2*)(P + o[i] + off);
                va[i] = u.x; vb[i] = u.y;
            } else {
                va[i] = P[o[i] + off];
            }
        }
        #pragma unroll
        for (int i = 0; i < 8; ++i) {
            const float m = (k0 + i < cnt) ? 1.f : 0.f;
            acc0 = fmaf(m, va[i], acc0);
            if (isDouble) acc1 = fmaf(m, vb[i], acc1);
        }
    }
    fsum[half][feat] = acc0;
    if (isDouble) fsum[half][feat + 1] = acc1;
    __syncthreads();

    // ---- Phase 2: h = mean @ W_agg + b_agg ; selfb = ch_v @ W_self + b ---
    const float invc = 1.0f / (float)cnt;
    if (j < H2) {
        float a = 0.f;
        #pragma unroll 8
        for (int f = 0; f < IN2; ++f)
            a = fmaf(fsum[half][f], W_agg[f * H2 + j], a);
        hbuf[half][j] = fmaf(a, invc, b_agg[j]);
    } else if (half == 0) {
        const int jj = j - 64;
        float a = b_self[jj];
        #pragma unroll 8
        for (int f = 0; f < IN1; ++f)
            a = fmaf(chv[f], W_self[f * H1 + jj], a);
        selfb[jj] = a;
    }
    __syncthreads();

    // ---- Phase 3: attention scores (b_attn2 cancels in 2-way softmax) ----
    float partial = 0.f;
    if (j < AH) {
        float u = b_attn[j];
        #pragma unroll 8
        for (int f = 0; f < H2; ++f)
            u = fmaf(hbuf[half][f], W_attn[f * AH + j], u);
        #pragma unroll 8
        for (int f = 0; f < IN1; ++f)
            u = fmaf(chv[f], W_attn[(H2 + f) * AH + j], u);
        partial = fmaxf(u, 0.f) * W_attn2[j];
    }
    #pragma unroll
    for (int off2 = 32; off2 > 0; off2 >>= 1)
        partial += __shfl_xor(partial, off2, 64);
    if ((t & 63) == 0) sred[half][(t >> 6) & 1] = partial;
    __syncthreads();

    // ---- Phase 4: 2-way softmax, convex combo, relu(concat) out ---------
    const float s0 = sred[0][0] + sred[0][1];
    const float s1 = sred[1][0] + sred[1][1];
    const float m  = fmaxf(s0, s1);
    const float ex0 = __expf(s0 - m), ex1 = __expf(s1 - m);
    const float rs  = 1.0f / (ex0 + ex1);
    const float a0 = ex0 * rs, a1 = ex1 * rs;
    if (t < H2) {
        const float g = a0 * hbuf[0][t] + a1 * hbuf[1][t];
        out[v * (H2 + H1) + t] = fmaxf(g, 0.f);
    } else if (t < H2 + H1) {
        out[v * (H2 + H1) + t] = fmaxf(selfb[t - H2], 0.f);
    }
}

extern "C" void kernel_launch(void* const* d_in, const int* in_sizes, int n_in,
                              void* d_out, int out_size, void* d_ws, size_t ws_size,
                              hipStream_t stream) {
    const float* channel_dense  = (const float*)d_in[0];
    const float* device_dense   = (const float*)d_in[1];
    const float* channel_id_emb = (const float*)d_in[2];
    const float* lang_emb       = (const float*)d_in[3];
    const float* plat_emb       = (const float*)d_in[4];
    const float* os_emb         = (const float*)d_in[5];
    const float* country_emb    = (const float*)d_in[6];
    const float* carrier_emb    = (const float*)d_in[7];
    const float* brand_emb      = (const float*)d_in[8];
    const float* plat_os_emb    = (const float*)d_in[9];
    const float* W_agg          = (const float*)d_in[10];
    const float* b_agg          = (const float*)d_in[11];
    const float* W_self         = (const float*)d_in[12];
    const float* b_self         = (const float*)d_in[13];
    const float* W_attn         = (const float*)d_in[14];
    const float* b_attn         = (const float*)d_in[15];
    const float* W_attn2        = (const float*)d_in[16];
    // d_in[17] = b_attn2: zero + cancels in 2-way softmax, unused
    const int* channel_ids   = (const int*)d_in[18];
    const int* device_cat    = (const int*)d_in[19];
    const int* vertices      = (const int*)d_in[20];
    const int* bot_neibrs    = (const int*)d_in[21];
    const int* normal_neibrs = (const int*)d_in[22];
    const int* bot_counts    = (const int*)d_in[23];
    const int* normal_counts = (const int*)d_in[24];
    float* out = (float*)d_out;

    gconv_kernel<<<dim3(BATCH), dim3(256), 0, stream>>>(
        channel_dense, device_dense, channel_id_emb,
        lang_emb, plat_emb, os_emb, country_emb, carrier_emb, brand_emb, plat_os_emb,
        W_agg, b_agg, W_self, b_self, W_attn, b_attn, W_attn2,
        channel_ids, device_cat, vertices, bot_neibrs, normal_neibrs,
        bot_counts, normal_counts, out);
}

// Round 4
// 94.164 us; speedup vs baseline: 2.8689x; 1.3477x over previous
//
#include <hip/hip_runtime.h>

#define BATCH 8192
#define KNB   64
#define EMB   16
#define CHD   16
#define DVD   20
#define H1    64
#define H2    64
#define AH    84
#define IN1   32
#define IN2   132

// ---------------------------------------------------------------------------
// K1: one block per (vertex, half). 256 threads = 4 waves.
//   Phase A : neighbor idx + cat offsets -> ofs[64][8]; chv -> LDS
//   Gather  : wave w owns neighbors k = w+4i; lane L owns features L, L+64
//             (+ masked 128+L for L<4). sched_barrier-fenced 4-deep batches
//             guarantee >=12 loads in flight per wave.
//   Matvec  : h partials split across 4 waves (33 f-iters each)
//   Score   : u partials split 2-ways over f (48 iters, 168 threads)
//   Writes h[b][64] and s[b] to workspace.
// ---------------------------------------------------------------------------
__global__ __launch_bounds__(256) void gconv_agg(
    const float* __restrict__ channel_dense,
    const float* __restrict__ device_dense,
    const float* __restrict__ channel_id_emb,
    const float* __restrict__ t0, const float* __restrict__ t1,
    const float* __restrict__ t2, const float* __restrict__ t3,
    const float* __restrict__ t4, const float* __restrict__ t5,
    const float* __restrict__ t6,
    const float* __restrict__ W_agg,  const float* __restrict__ b_agg,
    const float* __restrict__ W_attn, const float* __restrict__ b_attn,
    const float* __restrict__ W_attn2,
    const int* __restrict__ channel_ids,
    const int* __restrict__ device_cat,
    const int* __restrict__ vertices,
    const int* __restrict__ bot_neibrs,
    const int* __restrict__ normal_neibrs,
    const int* __restrict__ bot_counts,
    const int* __restrict__ normal_counts,
    float* __restrict__ h_ws,
    float* __restrict__ s_ws)
{
    const int b    = blockIdx.x;
    const int v    = b >> 1;
    const int half = b & 1;
    const int t    = threadIdx.x;
    const int w    = t >> 6;      // wave 0..3
    const int L    = t & 63;

    __shared__ alignas(16) int ofs[KNB][8]; // [k][slot]: 0=n*DVD, 1+c=cat_c*EMB
    __shared__ float chv[IN1];
    __shared__ float psum[4][IN2];
    __shared__ float hpart[4][H2];
    __shared__ float fsum[IN2];
    __shared__ float hsh[H2];
    __shared__ float upart[2][AH];
    __shared__ float sred[4];

    const int* neibrs = half ? normal_neibrs : bot_neibrs;
    int cnt = half ? normal_counts[v] : bot_counts[v];
    if (cnt > KNB) cnt = KNB;
    if (cnt < 1)   cnt = 1;

    // ---- Phase A ---------------------------------------------------------
    if (t < KNB) {
        int n = 0;
        if (t < cnt) n = neibrs[v * KNB + t];
        const long cb = (long)n * 7;
        const int c0 = device_cat[cb + 0];
        const int c1 = device_cat[cb + 1];
        const int c2 = device_cat[cb + 2];
        const int c3 = device_cat[cb + 3];
        const int c4 = device_cat[cb + 4];
        const int c5 = device_cat[cb + 5];
        const int c6 = device_cat[cb + 6];
        *(int4*)&ofs[t][0] = make_int4(n * DVD, c0 * EMB, c1 * EMB, c2 * EMB);
        *(int4*)&ofs[t][4] = make_int4(c3 * EMB, c4 * EMB, c5 * EMB, c6 * EMB);
    } else if (t < KNB + IN1) {
        const int c = t - KNB;
        const int vert = vertices[v];
        chv[c] = (c < CHD) ? channel_dense[vert * CHD + c]
                           : channel_id_emb[channel_ids[vert] * EMB + (c - CHD)];
    }
    __syncthreads(); // B1

    // ---- per-lane feature mapping (featA = L, featB = L+64, featC = 128+L)
    const float* PA; int sA, cA;
    if      (L < 20) { PA = device_dense; sA = 0; cA = L; }
    else if (L < 36) { PA = t0; sA = 1; cA = L - 20; }
    else if (L < 52) { PA = t1; sA = 2; cA = L - 36; }
    else             { PA = t2; sA = 3; cA = L - 52; }
    const float* PB; int sB, cB;
    if      (L < 4)  { PB = t2; sB = 3; cB = 12 + L; }
    else if (L < 20) { PB = t3; sB = 4; cB = L - 4; }
    else if (L < 36) { PB = t4; sB = 5; cB = L - 20; }
    else if (L < 52) { PB = t5; sB = 6; cB = L - 36; }
    else             { PB = t6; sB = 7; cB = L - 52; }
    const bool hasC = (L < 4);
    const int  cC   = hasC ? (12 + L) : 0;

    // ---- Gather: wave w handles k = w + 4*(i0+i) -------------------------
    float accA = 0.f, accB = 0.f, accC = 0.f;
    for (int i0 = 0; i0 < 16; i0 += 4) {
        if (w + 4 * i0 >= cnt) break;           // wave-uniform exit
        int oA[4], oB[4], oC[4];
        #pragma unroll
        for (int i = 0; i < 4; ++i) {
            const int k = w + 4 * (i0 + i);
            oA[i] = ofs[k][sA];
            oB[i] = ofs[k][sB];
            oC[i] = ofs[k][7];
        }
        __builtin_amdgcn_sched_barrier(0);
        float vA[4], vB[4], vC[4];
        #pragma unroll
        for (int i = 0; i < 4; ++i) {
            vA[i] = PA[oA[i] + cA];
            vB[i] = PB[oB[i] + cB];
            vC[i] = hasC ? t6[oC[i] + cC] : 0.f;
        }
        __builtin_amdgcn_sched_barrier(0);
        #pragma unroll
        for (int i = 0; i < 4; ++i) {
            const float m = (w + 4 * (i0 + i) < cnt) ? 1.f : 0.f;
            accA = fmaf(m, vA[i], accA);
            accB = fmaf(m, vB[i], accB);
            accC = fmaf(m, vC[i], accC);
        }
    }
    psum[w][L]      = accA;
    psum[w][L + 64] = accB;
    if (hasC) psum[w][128 + L] = accC;
    __syncthreads(); // B2

    if (t < IN2)
        fsum[t] = psum[0][t] + psum[1][t] + psum[2][t] + psum[3][t];
    __syncthreads(); // B3

    // ---- h matvec: wave w does f in [w*33, w*33+33) ----------------------
    {
        float a = 0.f;
        const int f0 = w * 33;
        #pragma unroll 8
        for (int i = 0; i < 33; ++i) {
            const int f = f0 + i;
            a = fmaf(fsum[f], W_agg[f * H2 + L], a);
        }
        hpart[w][L] = a;
    }
    __syncthreads(); // B4

    const float invc = 1.0f / (float)cnt;
    if (t < H2) {
        const float hv = fmaf(hpart[0][t] + hpart[1][t] + hpart[2][t] + hpart[3][t],
                              invc, b_agg[t]);
        hsh[t] = hv;
        h_ws[(size_t)b * H2 + t] = hv;
    }
    __syncthreads(); // B5

    // ---- attention score: 168 threads, 2-way f split ---------------------
    if (t < 2 * AH) {
        const int fh = (t >= AH) ? 1 : 0;
        const int aa = t - AH * fh;
        const int f0 = fh * 48;
        float u = 0.f;
        #pragma unroll 8
        for (int i = 0; i < 48; ++i) {
            const int f = f0 + i;
            const float x = (f < H2) ? hsh[f] : chv[f - H2];
            u = fmaf(x, W_attn[f * AH + aa], u);
        }
        upart[fh][aa] = u;
    }
    __syncthreads(); // B6

    float p = 0.f;
    if (t < AH) {
        const float u = upart[0][t] + upart[1][t] + b_attn[t];
        p = fmaxf(u, 0.f) * W_attn2[t];
    }
    #pragma unroll
    for (int off = 32; off > 0; off >>= 1)
        p += __shfl_xor(p, off, 64);
    if (L == 0) sred[w] = p;
    __syncthreads(); // B7
    if (t == 0) s_ws[b] = sred[0] + sred[1] + sred[2] + sred[3];
}

// ---------------------------------------------------------------------------
// K2: one block per vertex, 128 threads. Softmax over the two scores,
// convex-combine h, compute selfb = chv @ W_self + b_self, relu-concat out.
// ---------------------------------------------------------------------------
__global__ __launch_bounds__(128) void gconv_fin(
    const float* __restrict__ channel_dense,
    const float* __restrict__ channel_id_emb,
    const float* __restrict__ W_self, const float* __restrict__ b_self,
    const int* __restrict__ channel_ids,
    const int* __restrict__ vertices,
    const float* __restrict__ h_ws,
    const float* __restrict__ s_ws,
    float* __restrict__ out)
{
    const int v = blockIdx.x;
    const int t = threadIdx.x;
    __shared__ float chv[IN1];

    if (t < IN1) {
        const int vert = vertices[v];
        chv[t] = (t < CHD) ? channel_dense[vert * CHD + t]
                           : channel_id_emb[channel_ids[vert] * EMB + (t - CHD)];
    }
    const float s0 = s_ws[v * 2 + 0];
    const float s1 = s_ws[v * 2 + 1];
    const float m  = fmaxf(s0, s1);
    const float e0 = __expf(s0 - m), e1 = __expf(s1 - m);
    const float rs = 1.0f / (e0 + e1);
    const float a0 = e0 * rs, a1 = e1 * rs;
    __syncthreads();

    if (t < H2) {
        const float g = a0 * h_ws[(size_t)(v * 2 + 0) * H2 + t]
                      + a1 * h_ws[(size_t)(v * 2 + 1) * H2 + t];
        out[v * (H2 + H1) + t] = fmaxf(g, 0.f);
    } else {
        const int jj = t - H2;
        float a = b_self[jj];
        #pragma unroll 8
        for (int f = 0; f < IN1; ++f)
            a = fmaf(chv[f], W_self[f * H1 + jj], a);
        out[v * (H2 + H1) + H2 + jj] = fmaxf(a, 0.f);
    }
}

extern "C" void kernel_launch(void* const* d_in, const int* in_sizes, int n_in,
                              void* d_out, int out_size, void* d_ws, size_t ws_size,
                              hipStream_t stream) {
    const float* channel_dense  = (const float*)d_in[0];
    const float* device_dense   = (const float*)d_in[1];
    const float* channel_id_emb = (const float*)d_in[2];
    const float* lang_emb       = (const float*)d_in[3];
    const float* plat_emb       = (const float*)d_in[4];
    const float* os_emb         = (const float*)d_in[5];
    const float* country_emb    = (const float*)d_in[6];
    const float* carrier_emb    = (const float*)d_in[7];
    const float* brand_emb      = (const float*)d_in[8];
    const float* plat_os_emb    = (const float*)d_in[9];
    const float* W_agg          = (const float*)d_in[10];
    const float* b_agg          = (const float*)d_in[11];
    const float* W_self         = (const float*)d_in[12];
    const float* b_self         = (const float*)d_in[13];
    const float* W_attn         = (const float*)d_in[14];
    const float* b_attn         = (const float*)d_in[15];
    const float* W_attn2        = (const float*)d_in[16];
    // d_in[17] = b_attn2: zero + cancels in 2-way softmax, unused
    const int* channel_ids   = (const int*)d_in[18];
    const int* device_cat    = (const int*)d_in[19];
    const int* vertices      = (const int*)d_in[20];
    const int* bot_neibrs    = (const int*)d_in[21];
    const int* normal_neibrs = (const int*)d_in[22];
    const int* bot_counts    = (const int*)d_in[23];
    const int* normal_counts = (const int*)d_in[24];

    float* h_ws = (float*)d_ws;                          // [16384][64] = 4 MB
    float* s_ws = (float*)((char*)d_ws + (size_t)2 * BATCH * H2 * sizeof(float)); // 64 KB
    float* out  = (float*)d_out;

    gconv_agg<<<dim3(2 * BATCH), dim3(256), 0, stream>>>(
        channel_dense, device_dense, channel_id_emb,
        lang_emb, plat_emb, os_emb, country_emb, carrier_emb, brand_emb, plat_os_emb,
        W_agg, b_agg, W_attn, b_attn, W_attn2,
        channel_ids, device_cat, vertices, bot_neibrs, normal_neibrs,
        bot_counts, normal_counts, h_ws, s_ws);

    gconv_fin<<<dim3(BATCH), dim3(128), 0, stream>>>(
        channel_dense, channel_id_emb, W_self, b_self,
        channel_ids, vertices, h_ws, s_ws, out);
}

// Round 5
// 76.813 us; speedup vs baseline: 3.5170x; 1.2259x over previous
//
#include <hip/hip_runtime.h>

#define BATCH 8192
#define KNB   64
#define EMB   16
#define CHD   16
#define DVD   20
#define H1    64
#define H2    64
#define AH    84
#define IN1   32
#define IN2   132

#define RB 32   // b-rows per K2 block
#define VB 16   // vertices per K2 block

// ---------------------------------------------------------------------------
// K1: pure gather. One block per (vertex, half), 256 threads = 4 waves.
// 132 feats = 33 float4 slots (slot s -> feats 4s..4s+3):
//   s<5: device_dense cols 4s..4s+3 ; s>=5: table (s-5)>>2, cols ((s-5)&3)*4
//   s==32 (t6 cols 12..15) handled as masked extra by lanes with slot==0.
// Wave pass: lane L -> neighbor k = 2w+8i+(L>>5), slot = L&31. float4 loads,
// 4-deep sched_barrier-fenced batches. Output: raw fsum[b][132] to ws.
// ---------------------------------------------------------------------------
__global__ __launch_bounds__(256) void gconv_gather(
    const float* __restrict__ device_dense,
    const float* __restrict__ t0, const float* __restrict__ t1,
    const float* __restrict__ t2, const float* __restrict__ t3,
    const float* __restrict__ t4, const float* __restrict__ t5,
    const float* __restrict__ t6,
    const int* __restrict__ device_cat,
    const int* __restrict__ bot_neibrs,
    const int* __restrict__ normal_neibrs,
    const int* __restrict__ bot_counts,
    const int* __restrict__ normal_counts,
    float* __restrict__ fsum_ws)
{
    const int b    = blockIdx.x;
    const int v    = b >> 1;
    const int half = b & 1;
    const int t    = threadIdx.x;
    const int w    = t >> 6;
    const int L    = t & 63;

    __shared__ alignas(16) int   ofs[KNB][8];   // [k]: n*20, cat0*16..cat6*16
    __shared__ alignas(16) float psum[4][IN2];

    const int* neibrs = half ? normal_neibrs : bot_neibrs;
    int cnt = half ? normal_counts[v] : bot_counts[v];
    if (cnt > KNB) cnt = KNB;
    if (cnt < 1)   cnt = 1;

    // ---- Phase A: per-neighbor offsets -> LDS ---------------------------
    if (t < KNB) {
        int n = 0;
        if (t < cnt) n = neibrs[v * KNB + t];
        const long cb = (long)n * 7;
        const int c0 = device_cat[cb + 0];
        const int c1 = device_cat[cb + 1];
        const int c2 = device_cat[cb + 2];
        const int c3 = device_cat[cb + 3];
        const int c4 = device_cat[cb + 4];
        const int c5 = device_cat[cb + 5];
        const int c6 = device_cat[cb + 6];
        *(int4*)&ofs[t][0] = make_int4(n * DVD, c0 * EMB, c1 * EMB, c2 * EMB);
        *(int4*)&ofs[t][4] = make_int4(c3 * EMB, c4 * EMB, c5 * EMB, c6 * EMB);
    }
    __syncthreads();

    // ---- per-lane slot mapping ------------------------------------------
    const int kk   = L >> 5;       // neighbor parity within pass
    const int slot = L & 31;
    const float* P; int sIdx, c4v;
    if (slot < 5) {
        P = device_dense; sIdx = 0; c4v = slot * 4;
    } else {
        const int e = slot - 5;
        const int tsel = e >> 2;
        c4v = (e & 3) * 4; sIdx = 1 + tsel;
        switch (tsel) {
            case 0: P = t0; break;
            case 1: P = t1; break;
            case 2: P = t2; break;
            case 3: P = t3; break;
            case 4: P = t4; break;
            case 5: P = t5; break;
            default: P = t6; break;
        }
    }
    const bool xa = (slot == 0);   // lanes 0,32 also do slot 32 (t6 cols 12..15)

    float4 acc  = make_float4(0.f, 0.f, 0.f, 0.f);
    float4 accx = make_float4(0.f, 0.f, 0.f, 0.f);

    // ---- gather: k = 2w + 8i + kk, i = 0..7 in two 4-deep batches -------
    for (int i0 = 0; i0 < 8; i0 += 4) {
        if (2 * w + 8 * i0 >= cnt) break;            // wave-uniform
        int o[4], ox[4];
        #pragma unroll
        for (int i = 0; i < 4; ++i) {
            const int k = 2 * w + 8 * (i0 + i) + kk;
            o[i]  = ofs[k][sIdx];
            ox[i] = ofs[k][7];
        }
        __builtin_amdgcn_sched_barrier(0);
        float4 val[4], vx[4];
        #pragma unroll
        for (int i = 0; i < 4; ++i)
            val[i] = *(const float4*)(P + o[i] + c4v);
        if (xa) {
            #pragma unroll
            for (int i = 0; i < 4; ++i)
                vx[i] = *(const float4*)(t6 + ox[i] + 12);
        }
        __builtin_amdgcn_sched_barrier(0);
        #pragma unroll
        for (int i = 0; i < 4; ++i) {
            const int k = 2 * w + 8 * (i0 + i) + kk;
            const float m = (k < cnt) ? 1.f : 0.f;
            acc.x = fmaf(m, val[i].x, acc.x);
            acc.y = fmaf(m, val[i].y, acc.y);
            acc.z = fmaf(m, val[i].z, acc.z);
            acc.w = fmaf(m, val[i].w, acc.w);
            if (xa) {
                accx.x = fmaf(m, vx[i].x, accx.x);
                accx.y = fmaf(m, vx[i].y, accx.y);
                accx.z = fmaf(m, vx[i].z, accx.z);
                accx.w = fmaf(m, vx[i].w, accx.w);
            }
        }
    }

    // ---- combine neighbor-parity halves (lane L <-> L^32) ---------------
    acc.x += __shfl_xor(acc.x, 32, 64);
    acc.y += __shfl_xor(acc.y, 32, 64);
    acc.z += __shfl_xor(acc.z, 32, 64);
    acc.w += __shfl_xor(acc.w, 32, 64);
    accx.x += __shfl_xor(accx.x, 32, 64);
    accx.y += __shfl_xor(accx.y, 32, 64);
    accx.z += __shfl_xor(accx.z, 32, 64);
    accx.w += __shfl_xor(accx.w, 32, 64);

    if (L < 32) *(float4*)&psum[w][slot * 4] = acc;
    if (L == 0) *(float4*)&psum[w][128]      = accx;
    __syncthreads();

    if (t < IN2)
        fsum_ws[(size_t)b * IN2 + t] =
            psum[0][t] + psum[1][t] + psum[2][t] + psum[3][t];
}

// ---------------------------------------------------------------------------
// K2: all dense math for 32 b-rows (16 vertices) per block, 256 threads.
//   h  : wave w -> rows 8w..8w+7, lane = col; W_agg streamed (f-loop)
//   u  : threads 0..167 -> (aa, row-group of 16); acc[16]; W_attn coalesced
//   s  : 84-way LDS reduce; softmax per vertex pair
//   out: gcn combine + selfb (W_self float4) + relu, float4 stores
// ---------------------------------------------------------------------------
__global__ __launch_bounds__(256) void gconv_dense(
    const float* __restrict__ channel_dense,
    const float* __restrict__ channel_id_emb,
    const float* __restrict__ W_agg,  const float* __restrict__ b_agg,
    const float* __restrict__ W_self, const float* __restrict__ b_self,
    const float* __restrict__ W_attn, const float* __restrict__ b_attn,
    const float* __restrict__ W_attn2,
    const int* __restrict__ channel_ids,
    const int* __restrict__ vertices,
    const int* __restrict__ bot_counts,
    const int* __restrict__ normal_counts,
    const float* __restrict__ fsum_ws,
    float* __restrict__ out)
{
    const int blk = blockIdx.x;
    const int b0  = blk * RB;
    const int v0  = blk * VB;
    const int t   = threadIdx.x;

    __shared__ alignas(16) float fs[RB][IN2];      // 16.9 KB
    __shared__ alignas(16) float chvs[VB][IN1];    //  2 KB
    __shared__ alignas(16) float hs[RB][H2];       //  8 KB
    __shared__ float u_lds[AH][RB + 1];            // 11.1 KB (padded stride 33)
    __shared__ float sarr[RB];
    __shared__ float cinv[RB];

    // ---- stage fsum tile, counts, chv -----------------------------------
    for (int idx = t; idx < RB * IN2 / 4; idx += 256) {
        const float4 vv = *(const float4*)(fsum_ws + (size_t)b0 * IN2 + idx * 4);
        *(float4*)&((float*)fs)[idx * 4] = vv;
    }
    if (t < RB) {
        const int b = b0 + t;
        const int v = b >> 1;
        int c = (b & 1) ? normal_counts[v] : bot_counts[v];
        c = (c > KNB) ? KNB : ((c < 1) ? 1 : c);
        cinv[t] = 1.0f / (float)c;
    }
    if (t < 128) {
        const int vx = t >> 3, q = t & 7;
        const int vert = vertices[v0 + vx];
        const float* src = (q < 4)
            ? channel_dense  + (size_t)vert * CHD + q * 4
            : channel_id_emb + (size_t)channel_ids[vert] * EMB + (q - 4) * 4;
        *(float4*)&chvs[vx][q * 4] = *(const float4*)src;
    }
    __syncthreads();

    // ---- h = (fsum * invc) @ W_agg + b_agg ------------------------------
    {
        const int w = t >> 6, lane = t & 63;
        const int r0 = w * 8;
        float acc[8] = {0.f, 0.f, 0.f, 0.f, 0.f, 0.f, 0.f, 0.f};
        #pragma unroll 4
        for (int f = 0; f < IN2; ++f) {
            const float wv = W_agg[f * H2 + lane];
            #pragma unroll
            for (int r = 0; r < 8; ++r)
                acc[r] = fmaf(fs[r0 + r][f], wv, acc[r]);
        }
        const float bb = b_agg[lane];
        #pragma unroll
        for (int r = 0; r < 8; ++r)
            hs[r0 + r][lane] = fmaf(acc[r], cinv[r0 + r], bb);
    }
    __syncthreads();

    // ---- u[r][aa] = relu(concat(h,chv) @ W_attn + b_attn) * W_attn2 -----
    if (t < 2 * AH) {
        const int rg = (t >= AH) ? 1 : 0;
        const int aa = t - AH * rg;
        const int r0 = rg * 16;
        float acc[16];
        #pragma unroll
        for (int r = 0; r < 16; ++r) acc[r] = 0.f;
        #pragma unroll 2
        for (int f = 0; f < H2; ++f) {
            const float wv = W_attn[f * AH + aa];
            #pragma unroll
            for (int r = 0; r < 16; ++r)
                acc[r] = fmaf(hs[r0 + r][f], wv, acc[r]);
        }
        #pragma unroll 2
        for (int f = 0; f < IN1; ++f) {
            const float wv = W_attn[(H2 + f) * AH + aa];
            #pragma unroll
            for (int r = 0; r < 16; ++r)
                acc[r] = fmaf(chvs[(r0 + r) >> 1][f], wv, acc[r]);
        }
        const float ba = b_attn[aa], w2 = W_attn2[aa];
        #pragma unroll
        for (int r = 0; r < 16; ++r)
            u_lds[aa][r0 + r] = fmaxf(acc[r] + ba, 0.f) * w2;
    }
    __syncthreads();

    if (t < RB) {
        float s = 0.f;
        #pragma unroll 4
        for (int aa = 0; aa < AH; ++aa) s += u_lds[aa][t];
        sarr[t] = s;
    }
    __syncthreads();

    // ---- output: 2048 floats, 8 per thread ------------------------------
    {
        const int vl = t >> 4;
        const int c8 = (t & 15) * 8;
        const float s0 = sarr[2 * vl], s1 = sarr[2 * vl + 1];
        const float mm = fmaxf(s0, s1);
        const float e0 = __expf(s0 - mm), e1 = __expf(s1 - mm);
        const float rs = 1.0f / (e0 + e1);
        const float a0 = e0 * rs, a1 = e1 * rs;
        float o[8];
        if (c8 < H2) {
            #pragma unroll
            for (int c = 0; c < 8; ++c)
                o[c] = fmaxf(a0 * hs[2 * vl][c8 + c] + a1 * hs[2 * vl + 1][c8 + c], 0.f);
        } else {
            const int cs = c8 - H2;
            float accS[8];
            #pragma unroll
            for (int c = 0; c < 8; ++c) accS[c] = b_self[cs + c];
            #pragma unroll 4
            for (int f = 0; f < IN1; ++f) {
                const float xv = chvs[vl][f];
                const float4 wa = *(const float4*)(W_self + f * H1 + cs);
                const float4 wb = *(const float4*)(W_self + f * H1 + cs + 4);
                accS[0] = fmaf(xv, wa.x, accS[0]);
                accS[1] = fmaf(xv, wa.y, accS[1]);
                accS[2] = fmaf(xv, wa.z, accS[2]);
                accS[3] = fmaf(xv, wa.w, accS[3]);
                accS[4] = fmaf(xv, wb.x, accS[4]);
                accS[5] = fmaf(xv, wb.y, accS[5]);
                accS[6] = fmaf(xv, wb.z, accS[6]);
                accS[7] = fmaf(xv, wb.w, accS[7]);
            }
            #pragma unroll
            for (int c = 0; c < 8; ++c) o[c] = fmaxf(accS[c], 0.f);
        }
        float4* op = (float4*)(out + (size_t)(v0 + vl) * (H1 + H2) + c8);
        op[0] = make_float4(o[0], o[1], o[2], o[3]);
        op[1] = make_float4(o[4], o[5], o[6], o[7]);
    }
}

extern "C" void kernel_launch(void* const* d_in, const int* in_sizes, int n_in,
                              void* d_out, int out_size, void* d_ws, size_t ws_size,
                              hipStream_t stream) {
    const float* channel_dense  = (const float*)d_in[0];
    const float* device_dense   = (const float*)d_in[1];
    const float* channel_id_emb = (const float*)d_in[2];
    const float* lang_emb       = (const float*)d_in[3];
    const float* plat_emb       = (const float*)d_in[4];
    const float* os_emb         = (const float*)d_in[5];
    const float* country_emb    = (const float*)d_in[6];
    const float* carrier_emb    = (const float*)d_in[7];
    const float* brand_emb      = (const float*)d_in[8];
    const float* plat_os_emb    = (const float*)d_in[9];
    const float* W_agg          = (const float*)d_in[10];
    const float* b_agg          = (const float*)d_in[11];
    const float* W_self         = (const float*)d_in[12];
    const float* b_self         = (const float*)d_in[13];
    const float* W_attn         = (const float*)d_in[14];
    const float* b_attn         = (const float*)d_in[15];
    const float* W_attn2        = (const float*)d_in[16];
    // d_in[17] = b_attn2: zero + cancels in 2-way softmax, unused
    const int* channel_ids   = (const int*)d_in[18];
    const int* device_cat    = (const int*)d_in[19];
    const int* vertices      = (const int*)d_in[20];
    const int* bot_neibrs    = (const int*)d_in[21];
    const int* normal_neibrs = (const int*)d_in[22];
    const int* bot_counts    = (const int*)d_in[23];
    const int* normal_counts = (const int*)d_in[24];

    float* fsum_ws = (float*)d_ws;   // [16384][132] = 8.65 MB
    float* out     = (float*)d_out;

    gconv_gather<<<dim3(2 * BATCH), dim3(256), 0, stream>>>(
        device_dense, lang_emb, plat_emb, os_emb, country_emb, carrier_emb,
        brand_emb, plat_os_emb, device_cat, bot_neibrs, normal_neibrs,
        bot_counts, normal_counts, fsum_ws);

    gconv_dense<<<dim3(2 * BATCH / RB), dim3(256), 0, stream>>>(
        channel_dense, channel_id_emb, W_agg, b_agg, W_self, b_self,
        W_attn, b_attn, W_attn2, channel_ids, vertices,
        bot_counts, normal_counts, fsum_ws, out);
}

// Round 6
// 75.983 us; speedup vs baseline: 3.5554x; 1.0109x over previous
//
#include <hip/hip_runtime.h>

#define BATCH 8192
#define KNB   64
#define EMB   16
#define CHD   16
#define DVD   20
#define H1    64
#define H2    64
#define AH    84
#define IN1   32
#define IN2   132

#define RB 32    // b-rows per K2 block
#define VB 16    // vertices per K2 block
#define NIT 8    // items per persistent K1 block
#define NBLK (2 * BATCH / NIT)   // 2048

// ---------------------------------------------------------------------------
// K1: persistent gather. 2048 blocks x 8 items (item = (vertex,half) b-row).
//  - double-buffered ofs[2][64][8]; rotating wave stages item i+1's
//    idx->cat chain while the block gathers item i (latency hidden)
//  - cat row loaded as 2 overlapping int4 (2 instrs, not 7)
//  - plat_emb (4x16) staged in LDS once: 29 global float4 slots + 3 LDS lanes
//  feature layout: dense[0,20) lang[20) plat[36) os[52) country[68)
//                  carrier[84) brand[100) plat_os[116,132)
// ---------------------------------------------------------------------------
__global__ __launch_bounds__(256) void gconv_gather(
    const float* __restrict__ device_dense,
    const float* __restrict__ t0, const float* __restrict__ t1,
    const float* __restrict__ t2, const float* __restrict__ t3,
    const float* __restrict__ t4, const float* __restrict__ t5,
    const float* __restrict__ t6,
    const int* __restrict__ device_cat,
    const int* __restrict__ bot_neibrs,
    const int* __restrict__ normal_neibrs,
    const int* __restrict__ bot_counts,
    const int* __restrict__ normal_counts,
    float* __restrict__ fsum_ws)
{
    const int blk  = blockIdx.x;
    const int t    = threadIdx.x;
    const int w    = t >> 6;
    const int L    = t & 63;
    const int kk   = L >> 5;        // neighbor parity within pass
    const int slot = L & 31;

    __shared__ alignas(16) int   ofs[2][KNB][8];
    __shared__ alignas(16) float psum[4][IN2];
    __shared__ alignas(16) float plat_lds[64];
    __shared__ int scnt[2];

    // ---- one-time: plat table -> LDS ------------------------------------
    if (t < 64) plat_lds[t] = t1[t];

    // ---- per-lane slot mapping ------------------------------------------
    // slots 0..4: dense; 5..28: {lang,os,country,carrier,brand,plat_os};
    // slots 29..31: plat via LDS (lane 29 also covers plat cols 12..15)
    const float* P = device_dense;
    int sIdx = 0, c4v = slot * 4, fb = slot * 4;
    if (slot >= 5 && slot < 29) {
        const int e  = slot - 5;
        const int tb = e >> 2;                     // 0..5
        c4v  = (e & 3) * 4;
        sIdx = (tb == 0) ? 1 : (tb + 2);           // ofs slot
        fb   = 20 + 16 * ((tb == 0) ? 0 : tb + 1) + c4v;
        switch (tb) {
            case 0: P = t0; break;                 // lang
            case 1: P = t2; break;                 // os
            case 2: P = t3; break;                 // country
            case 3: P = t4; break;                 // carrier
            case 4: P = t5; break;                 // brand
            default: P = t6; break;                // plat_os
        }
    }
    const bool isPlat = (slot >= 29);
    const int  pcol   = (slot - 29) * 4;           // 0,4,8
    if (isPlat) fb = 36 + pcol;

    // ---- stage item -> buffer (one wave, rotating) ----------------------
    auto stage = [&](int it, int buf) {
        if (w != (it & 3)) return;
        const int b  = blk * NIT + it;
        const int v  = b >> 1;
        const bool nh = b & 1;
        int cnt = nh ? normal_counts[v] : bot_counts[v];
        cnt = cnt < 1 ? 1 : (cnt > KNB ? KNB : cnt);
        int n = 0;
        if (L < cnt) n = (nh ? normal_neibrs : bot_neibrs)[v * KNB + L];
        const long cb = (long)n * 7;
        const int4 cA = *(const int4*)(device_cat + cb);      // c0..c3
        const int4 cB = *(const int4*)(device_cat + cb + 3);  // c3..c6
        *(int4*)&ofs[buf][L][0] = make_int4(n * DVD, cA.x * EMB, cA.y * EMB, cA.z * EMB);
        *(int4*)&ofs[buf][L][4] = make_int4(cA.w * EMB, cB.y * EMB, cB.z * EMB, cB.w * EMB);
        if (L == 0) scnt[buf] = cnt;
    };

    stage(0, 0);
    __syncthreads();

    int buf = 0;
    for (int it = 0; it < NIT; ++it) {
        if (it + 1 < NIT) stage(it + 1, buf ^ 1);   // overlapped prefetch

        const int cnt = scnt[buf];
        float4 acc  = make_float4(0.f, 0.f, 0.f, 0.f);
        float4 accx = make_float4(0.f, 0.f, 0.f, 0.f);

        // gather: wave w covers k = 2w + 8j + kk, j in 2 chunks of 4
        #pragma unroll
        for (int c0 = 0; c0 < 8; c0 += 4) {
            if (2 * w + 8 * c0 >= cnt) break;        // wave-uniform skip
            const int kb = 2 * w + kk;
            if (!isPlat) {
                int o[4];
                #pragma unroll
                for (int i = 0; i < 4; ++i)
                    o[i] = ofs[buf][kb + 8 * (c0 + i)][sIdx];
                __builtin_amdgcn_sched_barrier(0);
                float4 val[4];
                #pragma unroll
                for (int i = 0; i < 4; ++i)
                    val[i] = *(const float4*)(P + o[i] + c4v);
                __builtin_amdgcn_sched_barrier(0);
                #pragma unroll
                for (int i = 0; i < 4; ++i) {
                    const float m = (kb + 8 * (c0 + i) < cnt) ? 1.f : 0.f;
                    acc.x = fmaf(m, val[i].x, acc.x);
                    acc.y = fmaf(m, val[i].y, acc.y);
                    acc.z = fmaf(m, val[i].z, acc.z);
                    acc.w = fmaf(m, val[i].w, acc.w);
                }
            } else {
                #pragma unroll
                for (int i = 0; i < 4; ++i) {
                    const int k = kb + 8 * (c0 + i);
                    const int o = ofs[buf][k][2];          // plat: c1*16
                    const float m = (k < cnt) ? 1.f : 0.f;
                    const float4 pv = *(const float4*)&plat_lds[o + pcol];
                    acc.x = fmaf(m, pv.x, acc.x);
                    acc.y = fmaf(m, pv.y, acc.y);
                    acc.z = fmaf(m, pv.z, acc.z);
                    acc.w = fmaf(m, pv.w, acc.w);
                    if (slot == 29) {
                        const float4 pw = *(const float4*)&plat_lds[o + 12];
                        accx.x = fmaf(m, pw.x, accx.x);
                        accx.y = fmaf(m, pw.y, accx.y);
                        accx.z = fmaf(m, pw.z, accx.z);
                        accx.w = fmaf(m, pw.w, accx.w);
                    }
                }
            }
        }

        // combine neighbor-parity halves (L <-> L^32)
        acc.x += __shfl_xor(acc.x, 32, 64);
        acc.y += __shfl_xor(acc.y, 32, 64);
        acc.z += __shfl_xor(acc.z, 32, 64);
        acc.w += __shfl_xor(acc.w, 32, 64);
        accx.x += __shfl_xor(accx.x, 32, 64);
        accx.y += __shfl_xor(accx.y, 32, 64);
        accx.z += __shfl_xor(accx.z, 32, 64);
        accx.w += __shfl_xor(accx.w, 32, 64);

        if (L < 32) {
            *(float4*)&psum[w][fb] = acc;
            if (slot == 29) *(float4*)&psum[w][48] = accx;
        }
        __syncthreads();   // B1: psum ready; stage(it+1) writes drained

        if (t < IN2 / 4) {
            const float4 p0 = *(const float4*)&psum[0][t * 4];
            const float4 p1 = *(const float4*)&psum[1][t * 4];
            const float4 p2 = *(const float4*)&psum[2][t * 4];
            const float4 p3 = *(const float4*)&psum[3][t * 4];
            const int b = blk * NIT + it;
            *(float4*)(fsum_ws + (size_t)b * IN2 + t * 4) =
                make_float4(p0.x + p1.x + p2.x + p3.x,
                            p0.y + p1.y + p2.y + p3.y,
                            p0.z + p1.z + p2.z + p3.z,
                            p0.w + p1.w + p2.w + p3.w);
        }
        __syncthreads();   // B2: psum reusable, ofs[buf^1] published
        buf ^= 1;
    }
}

// ---------------------------------------------------------------------------
// K2: all dense math for 32 b-rows (16 vertices) per block, 256 threads.
// ---------------------------------------------------------------------------
__global__ __launch_bounds__(256) void gconv_dense(
    const float* __restrict__ channel_dense,
    const float* __restrict__ channel_id_emb,
    const float* __restrict__ W_agg,  const float* __restrict__ b_agg,
    const float* __restrict__ W_self, const float* __restrict__ b_self,
    const float* __restrict__ W_attn, const float* __restrict__ b_attn,
    const float* __restrict__ W_attn2,
    const int* __restrict__ channel_ids,
    const int* __restrict__ vertices,
    const int* __restrict__ bot_counts,
    const int* __restrict__ normal_counts,
    const float* __restrict__ fsum_ws,
    float* __restrict__ out)
{
    const int blk = blockIdx.x;
    const int b0  = blk * RB;
    const int v0  = blk * VB;
    const int t   = threadIdx.x;

    __shared__ alignas(16) float fs[RB][IN2];
    __shared__ alignas(16) float chvs[VB][IN1];
    __shared__ alignas(16) float hs[RB][H2];
    __shared__ float u_lds[AH][RB + 1];
    __shared__ float sarr[RB];
    __shared__ float cinv[RB];

    for (int idx = t; idx < RB * IN2 / 4; idx += 256) {
        const float4 vv = *(const float4*)(fsum_ws + (size_t)b0 * IN2 + idx * 4);
        *(float4*)&((float*)fs)[idx * 4] = vv;
    }
    if (t < RB) {
        const int b = b0 + t;
        const int v = b >> 1;
        int c = (b & 1) ? normal_counts[v] : bot_counts[v];
        c = (c > KNB) ? KNB : ((c < 1) ? 1 : c);
        cinv[t] = 1.0f / (float)c;
    }
    if (t < 128) {
        const int vx = t >> 3, q = t & 7;
        const int vert = vertices[v0 + vx];
        const float* src = (q < 4)
            ? channel_dense  + (size_t)vert * CHD + q * 4
            : channel_id_emb + (size_t)channel_ids[vert] * EMB + (q - 4) * 4;
        *(float4*)&chvs[vx][q * 4] = *(const float4*)src;
    }
    __syncthreads();

    {
        const int w = t >> 6, lane = t & 63;
        const int r0 = w * 8;
        float acc[8] = {0.f, 0.f, 0.f, 0.f, 0.f, 0.f, 0.f, 0.f};
        #pragma unroll 4
        for (int f = 0; f < IN2; ++f) {
            const float wv = W_agg[f * H2 + lane];
            #pragma unroll
            for (int r = 0; r < 8; ++r)
                acc[r] = fmaf(fs[r0 + r][f], wv, acc[r]);
        }
        const float bb = b_agg[lane];
        #pragma unroll
        for (int r = 0; r < 8; ++r)
            hs[r0 + r][lane] = fmaf(acc[r], cinv[r0 + r], bb);
    }
    __syncthreads();

    if (t < 2 * AH) {
        const int rg = (t >= AH) ? 1 : 0;
        const int aa = t - AH * rg;
        const int r0 = rg * 16;
        float acc[16];
        #pragma unroll
        for (int r = 0; r < 16; ++r) acc[r] = 0.f;
        #pragma unroll 2
        for (int f = 0; f < H2; ++f) {
            const float wv = W_attn[f * AH + aa];
            #pragma unroll
            for (int r = 0; r < 16; ++r)
                acc[r] = fmaf(hs[r0 + r][f], wv, acc[r]);
        }
        #pragma unroll 2
        for (int f = 0; f < IN1; ++f) {
            const float wv = W_attn[(H2 + f) * AH + aa];
            #pragma unroll
            for (int r = 0; r < 16; ++r)
                acc[r] = fmaf(chvs[(r0 + r) >> 1][f], wv, acc[r]);
        }
        const float ba = b_attn[aa], w2 = W_attn2[aa];
        #pragma unroll
        for (int r = 0; r < 16; ++r)
            u_lds[aa][r0 + r] = fmaxf(acc[r] + ba, 0.f) * w2;
    }
    __syncthreads();

    if (t < RB) {
        float s = 0.f;
        #pragma unroll 4
        for (int aa = 0; aa < AH; ++aa) s += u_lds[aa][t];
        sarr[t] = s;
    }
    __syncthreads();

    {
        const int vl = t >> 4;
        const int c8 = (t & 15) * 8;
        const float s0 = sarr[2 * vl], s1 = sarr[2 * vl + 1];
        const float mm = fmaxf(s0, s1);
        const float e0 = __expf(s0 - mm), e1 = __expf(s1 - mm);
        const float rs = 1.0f / (e0 + e1);
        const float a0 = e0 * rs, a1 = e1 * rs;
        float o[8];
        if (c8 < H2) {
            #pragma unroll
            for (int c = 0; c < 8; ++c)
                o[c] = fmaxf(a0 * hs[2 * vl][c8 + c] + a1 * hs[2 * vl + 1][c8 + c], 0.f);
        } else {
            const int cs = c8 - H2;
            float accS[8];
            #pragma unroll
            for (int c = 0; c < 8; ++c) accS[c] = b_self[cs + c];
            #pragma unroll 4
            for (int f = 0; f < IN1; ++f) {
                const float xv = chvs[vl][f];
                const float4 wa = *(const float4*)(W_self + f * H1 + cs);
                const float4 wb = *(const float4*)(W_self + f * H1 + cs + 4);
                accS[0] = fmaf(xv, wa.x, accS[0]);
                accS[1] = fmaf(xv, wa.y, accS[1]);
                accS[2] = fmaf(xv, wa.z, accS[2]);
                accS[3] = fmaf(xv, wa.w, accS[3]);
                accS[4] = fmaf(xv, wb.x, accS[4]);
                accS[5] = fmaf(xv, wb.y, accS[5]);
                accS[6] = fmaf(xv, wb.z, accS[6]);
                accS[7] = fmaf(xv, wb.w, accS[7]);
            }
            #pragma unroll
            for (int c = 0; c < 8; ++c) o[c] = fmaxf(accS[c], 0.f);
        }
        float4* op = (float4*)(out + (size_t)(v0 + vl) * (H1 + H2) + c8);
        op[0] = make_float4(o[0], o[1], o[2], o[3]);
        op[1] = make_float4(o[4], o[5], o[6], o[7]);
    }
}

extern "C" void kernel_launch(void* const* d_in, const int* in_sizes, int n_in,
                              void* d_out, int out_size, void* d_ws, size_t ws_size,
                              hipStream_t stream) {
    const float* channel_dense  = (const float*)d_in[0];
    const float* device_dense   = (const float*)d_in[1];
    const float* channel_id_emb = (const float*)d_in[2];
    const float* lang_emb       = (const float*)d_in[3];
    const float* plat_emb       = (const float*)d_in[4];
    const float* os_emb         = (const float*)d_in[5];
    const float* country_emb    = (const float*)d_in[6];
    const float* carrier_emb    = (const float*)d_in[7];
    const float* brand_emb      = (const float*)d_in[8];
    const float* plat_os_emb    = (const float*)d_in[9];
    const float* W_agg          = (const float*)d_in[10];
    const float* b_agg          = (const float*)d_in[11];
    const float* W_self         = (const float*)d_in[12];
    const float* b_self         = (const float*)d_in[13];
    const float* W_attn         = (const float*)d_in[14];
    const float* b_attn         = (const float*)d_in[15];
    const float* W_attn2        = (const float*)d_in[16];
    // d_in[17] = b_attn2: zero + cancels in 2-way softmax, unused
    const int* channel_ids   = (const int*)d_in[18];
    const int* device_cat    = (const int*)d_in[19];
    const int* vertices      = (const int*)d_in[20];
    const int* bot_neibrs    = (const int*)d_in[21];
    const int* normal_neibrs = (const int*)d_in[22];
    const int* bot_counts    = (const int*)d_in[23];
    const int* normal_counts = (const int*)d_in[24];

    float* fsum_ws = (float*)d_ws;   // [16384][132] = 8.65 MB
    float* out     = (float*)d_out;

    gconv_gather<<<dim3(NBLK), dim3(256), 0, stream>>>(
        device_dense, lang_emb, plat_emb, os_emb, country_emb, carrier_emb,
        brand_emb, plat_os_emb, device_cat, bot_neibrs, normal_neibrs,
        bot_counts, normal_counts, fsum_ws);

    gconv_dense<<<dim3(2 * BATCH / RB), dim3(256), 0, stream>>>(
        channel_dense, channel_id_emb, W_agg, b_agg, W_self, b_self,
        W_attn, b_attn, W_attn2, channel_ids, vertices,
        bot_counts, normal_counts, fsum_ws, out);
}